// Round 4
// baseline (91.975 us; speedup 1.0000x reference)
//
#include <hip/hip_runtime.h>
#include <hip/hip_bf16.h>
#include <hip/hip_cooperative_groups.h>

namespace cg = cooperative_groups;

#define S_LEN   512
#define NSTEP   511
#define B_SZ    64
#define SIG_PG  4368     // 16 + 256 + 4096
#define SIG_TOT 8736
#define HIDDEN  256
#define OUT_CH  32
#define KC      128
#define KLEN    69       // ceil(8736/128)

// ===========================================================================
// Fully fused cooperative kernel: 256 blocks x 1024 threads (1 block/CU).
//   Phase 1 (blocks 0..63): depth-3 core signature + M^{(x)k} expansion.
//   grid.sync()
//   Phase 2 (all blocks):   sig @ w1 partials (block = kc x hidden-half).
//   grid.sync()
//   Phase 3 (blocks 0..63): reduce partials + bias + ReLU + h @ w2 + b2.
// ===========================================================================
__global__ __launch_bounds__(1024) void fused_all(
    const float* __restrict__ x,          // (64, 512, 3)
    const void*  __restrict__ lengths_raw,// (64,) int32 or int64
    const float* __restrict__ aug_w,      // (2, 12, 3)
    const float* __restrict__ w1,         // (8736, 256)
    const float* __restrict__ b1,         // (256,)
    const float* __restrict__ w2,         // (256, 32)
    const float* __restrict__ b2,         // (32,)
    float* __restrict__ sig,              // ws (64, 8736)
    float* __restrict__ hpart,            // ws (128, 64, 256)
    float* __restrict__ outp)             // (64, 32)
{
    cg::grid_group grid = cg::this_grid();

    __shared__ union alignas(16) {
        struct {                      // all sizes multiples of 16 B
            float xs[S_LEN * 3];      // 6144 B
            float u[NSTEP * 4 + 4];   // 8192 B
            float segsig[16 * 88];    // 5632 B
            float cs[88];             // 352 B
            float M[2][16][4];        // 512 B
            float W1[2][256];         // 2048 B
            float W2[2][1024];        // 8192 B
            float V1[2][64];          // 512 B
            float S1[2][16];          // 128 B
        } p1;
        struct {
            float s_sig[64 * 70];     // 17920 B
        } p2;
        struct {
            float sp[4][HIDDEN];
            float s_h[HIDDEN];
            float s_p[8][33];
        } p3;
    } sm;

    const int bx  = blockIdx.x;
    const int tid = threadIdx.x;

    // ------------------------------ Phase 1 ------------------------------
    if (bx < B_SZ) {
        const int b = bx;

        // lengths dtype detect: all lengths >= 2 -> if word1 == 0 it's int64.
        const int* l32 = (const int*)lengths_raw;
        const int  len = (l32[1] == 0) ? l32[2 * b] : l32[b];
        const int  lastIdx = len - 1;

        if (tid < 384)
            ((float4*)sm.p1.xs)[tid] = ((const float4*)(x + (size_t)b * S_LEN * 3))[tid];
        if (tid >= 512 && tid < 544) {
            const int t2 = tid - 512, g = t2 >> 4, row = t2 & 15;
            float4 m;
            if (row == 0)      m = make_float4(1.f, 0.f, 0.f, 0.f);
            else if (row < 4)  m = make_float4(0.f, row == 1 ? 1.f : 0.f,
                                                    row == 2 ? 1.f : 0.f,
                                                    row == 3 ? 1.f : 0.f);
            else {
                const float* aw = aug_w + g * 36 + (row - 4) * 3;
                m = make_float4(0.f, aw[0], aw[1], aw[2]);
            }
            *(float4*)&sm.p1.M[g][row][0] = m;
        }
        __syncthreads();

        if (tid < NSTEP) {
            const int s = tid;
            float dx0 = 0.f, dx1 = 0.f, dx2 = 0.f;
            if (s < lastIdx) {             // become-constant trick => dx = 0
                dx0 = sm.p1.xs[(s + 1) * 3 + 0] - sm.p1.xs[s * 3 + 0];
                dx1 = sm.p1.xs[(s + 1) * 3 + 1] - sm.p1.xs[s * 3 + 1];
                dx2 = sm.p1.xs[(s + 1) * 3 + 2] - sm.p1.xs[s * 3 + 2];
            }
            *(float4*)&sm.p1.u[s * 4] = make_float4(1.0f / 511.0f, dx0, dx1, dx2);
        }
        __syncthreads();

        // per-wave 32-step core segment scan (thread = tensor index (a,bb,c))
        const int wid  = tid >> 6, lane = tid & 63;
        const int a    = lane >> 4;
        const int bb   = (lane >> 2) & 3;
        const int c    = lane & 3;
        {
            const int s0   = wid * 32;
            const int nloc = min(32, NSTEP - s0);   // 32 (waves 0-14), 31 (wave 15)
            float r1 = 0.f, r2 = 0.f, r3 = 0.f;
            for (int s = s0; s < s0 + nloc; ++s) {
                const float da = sm.p1.u[s * 4 + a];
                const float db = sm.p1.u[s * 4 + bb];
                const float dc = sm.p1.u[s * 4 + c];
                const float t  = fmaf(db, fmaf(r1, 0.5f, da * (1.f / 6.f)), r2);
                r3 = fmaf(t, dc, r3);
                r2 = fmaf(db, fmaf(da, 0.5f, r1), r2);
                r1 += da;
            }
            sm.p1.segsig[wid * 88 + 20 + lane] = r3;
            if (c == 0)            sm.p1.segsig[wid * 88 + 4 + a * 4 + bb] = r2;
            if (bb == 0 && c == 0) sm.p1.segsig[wid * 88 + a]              = r1;
        }
        __syncthreads();

        // wave 0: serial Chen combine of 16 segments
        if (wid == 0) {
            float A1 = sm.p1.segsig[a];
            float A2 = sm.p1.segsig[4 + a * 4 + bb];
            float A3 = sm.p1.segsig[20 + lane];
            for (int sg = 1; sg < 16; ++sg) {
                const float* S = &sm.p1.segsig[sg * 88];
                const float B1a  = S[a];
                const float B1b  = S[bb];
                const float B1c  = S[c];
                const float B2ab = S[4 + a * 4 + bb];
                const float B2bc = S[4 + bb * 4 + c];
                const float B3   = S[20 + lane];
                A3 = fmaf(A1, B2bc, fmaf(A2, B1c, A3 + B3));  // OLD A1, A2
                A2 = fmaf(A1, B1b, A2 + B2ab);                // OLD A1
                A1 = A1 + B1a;
            }
            sm.p1.cs[20 + lane] = A3;
            if (c == 0)            sm.p1.cs[4 + a * 4 + bb] = A2;
            if (bb == 0 && c == 0) sm.p1.cs[a]              = A1;
        }
        __syncthreads();

        // expansion stage 1
        if (tid < 512) {
            const int g = tid >> 8, rem = tid & 255;
            const int i = rem >> 4, bc = rem & 15;
            const float4 m = *(const float4*)&sm.p1.M[g][i][0];
            sm.p1.W1[g][rem] = fmaf(m.x, sm.p1.cs[20 + bc],
                               fmaf(m.y, sm.p1.cs[20 + 16 + bc],
                               fmaf(m.z, sm.p1.cs[20 + 32 + bc],
                                     m.w * sm.p1.cs[20 + 48 + bc])));
        } else if (tid < 640) {
            const int rem = tid - 512;
            const int g = rem >> 6, r2i = rem & 63;
            const int i = r2i >> 2, bq = r2i & 3;
            const float4 m = *(const float4*)&sm.p1.M[g][i][0];
            sm.p1.V1[g][r2i] = fmaf(m.x, sm.p1.cs[4 + bq],
                               fmaf(m.y, sm.p1.cs[4 + 4 + bq],
                               fmaf(m.z, sm.p1.cs[4 + 8 + bq],
                                     m.w * sm.p1.cs[4 + 12 + bq])));
        } else if (tid < 672) {
            const int rem = tid - 640;
            const int g = rem >> 4, i = rem & 15;
            const float4 m = *(const float4*)&sm.p1.M[g][i][0];
            sm.p1.S1[g][i] = fmaf(m.x, sm.p1.cs[0], fmaf(m.y, sm.p1.cs[1],
                             fmaf(m.z, sm.p1.cs[2], m.w * sm.p1.cs[3])));
        }
        __syncthreads();

        // expansion stage 2
        #pragma unroll
        for (int rep = 0; rep < 2; ++rep) {
            const int e = tid + rep * 1024;
            const int g = e >> 10, rem = e & 1023;
            const int i = rem >> 6, j = (rem >> 2) & 15, cc = rem & 3;
            const float4 m = *(const float4*)&sm.p1.M[g][j][0];
            sm.p1.W2[g][rem] = fmaf(m.x, sm.p1.W1[g][i * 16 + cc],
                               fmaf(m.y, sm.p1.W1[g][i * 16 + 4 + cc],
                               fmaf(m.z, sm.p1.W1[g][i * 16 + 8 + cc],
                                     m.w * sm.p1.W1[g][i * 16 + 12 + cc])));
        }
        __syncthreads();

        // expansion stage 3 + write sig
        if (tid < 512) {
            const int g = tid >> 8, rem = tid & 255;
            const int i = rem >> 4, j = rem & 15;
            float* out = sig + (size_t)b * SIG_TOT + (size_t)g * SIG_PG;

            const float4 wv = *(const float4*)&sm.p1.W2[g][i * 64 + j * 4];
            float4* o3 = (float4*)(out + 272 + (size_t)(i * 16 + j) * 16);
            #pragma unroll
            for (int kq = 0; kq < 4; ++kq) {
                float4 r;
                const float4 m0 = *(const float4*)&sm.p1.M[g][kq * 4 + 0][0];
                const float4 m1 = *(const float4*)&sm.p1.M[g][kq * 4 + 1][0];
                const float4 m2 = *(const float4*)&sm.p1.M[g][kq * 4 + 2][0];
                const float4 m3 = *(const float4*)&sm.p1.M[g][kq * 4 + 3][0];
                r.x = fmaf(m0.x, wv.x, fmaf(m0.y, wv.y, fmaf(m0.z, wv.z, m0.w * wv.w)));
                r.y = fmaf(m1.x, wv.x, fmaf(m1.y, wv.y, fmaf(m1.z, wv.z, m1.w * wv.w)));
                r.z = fmaf(m2.x, wv.x, fmaf(m2.y, wv.y, fmaf(m2.z, wv.z, m2.w * wv.w)));
                r.w = fmaf(m3.x, wv.x, fmaf(m3.y, wv.y, fmaf(m3.z, wv.z, m3.w * wv.w)));
                o3[kq] = r;
            }

            const float4 v1 = *(const float4*)&sm.p1.V1[g][i * 4];
            const float4 mj = *(const float4*)&sm.p1.M[g][j][0];
            out[16 + i * 16 + j] =
                fmaf(mj.x, v1.x, fmaf(mj.y, v1.y, fmaf(mj.z, v1.z, mj.w * v1.w)));

            if (j == 0) out[i] = sm.p1.S1[g][i];
        }
    }

    grid.sync();

    // ------------------------------ Phase 2 ------------------------------
    // block bx: kc = bx>>1 (0..127), half = bx&1 (128 hidden cols).
    // thread: hq = tid&31 -> col half*128 + hq*4; bg = tid>>5 -> rows bg, bg+32.
    {
        const int kc   = bx >> 1;
        const int half = bx & 1;
        const int hq   = tid & 31;
        const int bg   = tid >> 5;

        const int k0   = kc * KLEN;
        const int klen = min(KLEN, SIG_TOT - k0);   // negative for kc==127 tail

        for (int idx = tid; idx < 64 * KLEN; idx += 1024) {
            const int rb = idx / KLEN, kk = idx - rb * KLEN;
            if (kk < klen)
                sm.p2.s_sig[rb * 70 + kk] = sig[(size_t)rb * SIG_TOT + k0 + kk];
        }
        __syncthreads();

        float4 acc0 = make_float4(0.f, 0.f, 0.f, 0.f);
        float4 acc1 = acc0;

        const float* wp = w1 + (size_t)k0 * HIDDEN + half * 128 + hq * 4;
        #pragma unroll 4
        for (int k = 0; k < klen; ++k) {
            const float4 wv = *(const float4*)(wp + (size_t)k * HIDDEN);
            const float sv0 = sm.p2.s_sig[(bg     ) * 70 + k];
            const float sv1 = sm.p2.s_sig[(bg + 32) * 70 + k];
            acc0.x = fmaf(sv0, wv.x, acc0.x); acc0.y = fmaf(sv0, wv.y, acc0.y);
            acc0.z = fmaf(sv0, wv.z, acc0.z); acc0.w = fmaf(sv0, wv.w, acc0.w);
            acc1.x = fmaf(sv1, wv.x, acc1.x); acc1.y = fmaf(sv1, wv.y, acc1.y);
            acc1.z = fmaf(sv1, wv.z, acc1.z); acc1.w = fmaf(sv1, wv.w, acc1.w);
        }

        const int hcol = half * 128 + hq * 4;
        *(float4*)(hpart + ((size_t)kc * 64 + bg     ) * HIDDEN + hcol) = acc0;
        *(float4*)(hpart + ((size_t)kc * 64 + bg + 32) * HIDDEN + hcol) = acc1;
        __syncthreads();
    }

    grid.sync();

    // ------------------------------ Phase 3 ------------------------------
    if (bx < B_SZ) {
        const int b = bx;
        const int h = tid & 255, q = tid >> 8;

        float acc = 0.f;
        #pragma unroll 8
        for (int m = 0; m < 32; ++m) {
            const int kc = q * 32 + m;
            acc += hpart[((size_t)kc * 64 + b) * HIDDEN + h];
        }
        sm.p3.sp[q][h] = acc;
        __syncthreads();

        if (tid < HIDDEN) {
            const float v = b1[tid] + sm.p3.sp[0][tid] + sm.p3.sp[1][tid]
                          + sm.p3.sp[2][tid] + sm.p3.sp[3][tid];
            sm.p3.s_h[tid] = fmaxf(v, 0.f);
        }
        __syncthreads();

        if (tid < 256) {
            const int o = tid & 31, part = tid >> 5;
            float p = 0.f;
            #pragma unroll
            for (int jj = 0; jj < 32; ++jj)
                p = fmaf(sm.p3.s_h[part * 32 + jj], w2[(part * 32 + jj) * OUT_CH + o], p);
            sm.p3.s_p[part][o] = p;
        }
        __syncthreads();

        if (tid < OUT_CH) {
            float oacc = b2[tid];
            #pragma unroll
            for (int pp = 0; pp < 8; ++pp) oacc += sm.p3.s_p[pp][tid];
            outp[b * OUT_CH + tid] = oacc;
        }
    }
}

// ===========================================================================
// Fallback path (R3 structure, verified) in case cooperative launch is
// rejected during graph capture.
// ===========================================================================
__global__ __launch_bounds__(1024) void sig_fused_kernel(
    const float* __restrict__ x, const void* __restrict__ lengths_raw,
    const float* __restrict__ aug_w, float* __restrict__ sig_out)
{
    __shared__ alignas(16) float xs[S_LEN * 3];
    __shared__ alignas(16) float u[NSTEP * 4];
    __shared__ float segsig[16 * 88];
    __shared__ float cs[88];
    __shared__ alignas(16) float M[2][16][4];
    __shared__ alignas(16) float W1[2][256];
    __shared__ alignas(16) float W2[2][1024];
    __shared__ alignas(16) float V1[2][64];
    __shared__ float S1[2][16];

    const int b   = blockIdx.x;
    const int tid = threadIdx.x;

    const int* l32 = (const int*)lengths_raw;
    const int  len = (l32[1] == 0) ? l32[2 * b] : l32[b];
    const int  lastIdx = len - 1;

    if (tid < 384)
        ((float4*)xs)[tid] = ((const float4*)(x + (size_t)b * S_LEN * 3))[tid];
    if (tid >= 512 && tid < 544) {
        const int t2 = tid - 512, g = t2 >> 4, row = t2 & 15;
        float4 m;
        if (row == 0)      m = make_float4(1.f, 0.f, 0.f, 0.f);
        else if (row < 4)  m = make_float4(0.f, row == 1 ? 1.f : 0.f,
                                                row == 2 ? 1.f : 0.f,
                                                row == 3 ? 1.f : 0.f);
        else {
            const float* aw = aug_w + g * 36 + (row - 4) * 3;
            m = make_float4(0.f, aw[0], aw[1], aw[2]);
        }
        *(float4*)&M[g][row][0] = m;
    }
    __syncthreads();

    if (tid < NSTEP) {
        const int s = tid;
        float dx0 = 0.f, dx1 = 0.f, dx2 = 0.f;
        if (s < lastIdx) {
            dx0 = xs[(s + 1) * 3 + 0] - xs[s * 3 + 0];
            dx1 = xs[(s + 1) * 3 + 1] - xs[s * 3 + 1];
            dx2 = xs[(s + 1) * 3 + 2] - xs[s * 3 + 2];
        }
        *(float4*)&u[s * 4] = make_float4(1.0f / 511.0f, dx0, dx1, dx2);
    }
    __syncthreads();

    const int wid  = tid >> 6, lane = tid & 63;
    const int a    = lane >> 4;
    const int bb   = (lane >> 2) & 3;
    const int c    = lane & 3;
    {
        const int s0   = wid * 32;
        const int nloc = min(32, NSTEP - s0);
        float r1 = 0.f, r2 = 0.f, r3 = 0.f;
        for (int s = s0; s < s0 + nloc; ++s) {
            const float da = u[s * 4 + a];
            const float db = u[s * 4 + bb];
            const float dc = u[s * 4 + c];
            const float t  = fmaf(db, fmaf(r1, 0.5f, da * (1.f / 6.f)), r2);
            r3 = fmaf(t, dc, r3);
            r2 = fmaf(db, fmaf(da, 0.5f, r1), r2);
            r1 += da;
        }
        segsig[wid * 88 + 20 + lane] = r3;
        if (c == 0)            segsig[wid * 88 + 4 + a * 4 + bb] = r2;
        if (bb == 0 && c == 0) segsig[wid * 88 + a]              = r1;
    }
    __syncthreads();

    if (wid == 0) {
        float A1 = segsig[a];
        float A2 = segsig[4 + a * 4 + bb];
        float A3 = segsig[20 + lane];
        for (int sg = 1; sg < 16; ++sg) {
            const float* S = &segsig[sg * 88];
            const float B1a  = S[a];
            const float B1b  = S[bb];
            const float B1c  = S[c];
            const float B2ab = S[4 + a * 4 + bb];
            const float B2bc = S[4 + bb * 4 + c];
            const float B3   = S[20 + lane];
            A3 = fmaf(A1, B2bc, fmaf(A2, B1c, A3 + B3));
            A2 = fmaf(A1, B1b, A2 + B2ab);
            A1 = A1 + B1a;
        }
        cs[20 + lane] = A3;
        if (c == 0)            cs[4 + a * 4 + bb] = A2;
        if (bb == 0 && c == 0) cs[a]              = A1;
    }
    __syncthreads();

    if (tid < 512) {
        const int g = tid >> 8, rem = tid & 255;
        const int i = rem >> 4, bc = rem & 15;
        const float4 m = *(const float4*)&M[g][i][0];
        W1[g][rem] = fmaf(m.x, cs[20 + bc],
                     fmaf(m.y, cs[20 + 16 + bc],
                     fmaf(m.z, cs[20 + 32 + bc],
                           m.w * cs[20 + 48 + bc])));
    } else if (tid < 640) {
        const int rem = tid - 512;
        const int g = rem >> 6, r2i = rem & 63;
        const int i = r2i >> 2, bq = r2i & 3;
        const float4 m = *(const float4*)&M[g][i][0];
        V1[g][r2i] = fmaf(m.x, cs[4 + bq],
                     fmaf(m.y, cs[4 + 4 + bq],
                     fmaf(m.z, cs[4 + 8 + bq],
                           m.w * cs[4 + 12 + bq])));
    } else if (tid < 672) {
        const int rem = tid - 640;
        const int g = rem >> 4, i = rem & 15;
        const float4 m = *(const float4*)&M[g][i][0];
        S1[g][i] = fmaf(m.x, cs[0], fmaf(m.y, cs[1], fmaf(m.z, cs[2], m.w * cs[3])));
    }
    __syncthreads();

    #pragma unroll
    for (int rep = 0; rep < 2; ++rep) {
        const int e = tid + rep * 1024;
        const int g = e >> 10, rem = e & 1023;
        const int i = rem >> 6, j = (rem >> 2) & 15, cc = rem & 3;
        const float4 m = *(const float4*)&M[g][j][0];
        W2[g][rem] = fmaf(m.x, W1[g][i * 16 + cc],
                     fmaf(m.y, W1[g][i * 16 + 4 + cc],
                     fmaf(m.z, W1[g][i * 16 + 8 + cc],
                           m.w * W1[g][i * 16 + 12 + cc])));
    }
    __syncthreads();

    if (tid < 512) {
        const int g = tid >> 8, rem = tid & 255;
        const int i = rem >> 4, j = rem & 15;
        float* out = sig_out + (size_t)b * SIG_TOT + (size_t)g * SIG_PG;

        const float4 wv = *(const float4*)&W2[g][i * 64 + j * 4];
        float4* o3 = (float4*)(out + 272 + (size_t)(i * 16 + j) * 16);
        #pragma unroll
        for (int kq = 0; kq < 4; ++kq) {
            float4 r;
            const float4 m0 = *(const float4*)&M[g][kq * 4 + 0][0];
            const float4 m1 = *(const float4*)&M[g][kq * 4 + 1][0];
            const float4 m2 = *(const float4*)&M[g][kq * 4 + 2][0];
            const float4 m3 = *(const float4*)&M[g][kq * 4 + 3][0];
            r.x = fmaf(m0.x, wv.x, fmaf(m0.y, wv.y, fmaf(m0.z, wv.z, m0.w * wv.w)));
            r.y = fmaf(m1.x, wv.x, fmaf(m1.y, wv.y, fmaf(m1.z, wv.z, m1.w * wv.w)));
            r.z = fmaf(m2.x, wv.x, fmaf(m2.y, wv.y, fmaf(m2.z, wv.z, m2.w * wv.w)));
            r.w = fmaf(m3.x, wv.x, fmaf(m3.y, wv.y, fmaf(m3.z, wv.z, m3.w * wv.w)));
            o3[kq] = r;
        }

        const float4 v1 = *(const float4*)&V1[g][i * 4];
        const float4 mj = *(const float4*)&M[g][j][0];
        out[16 + i * 16 + j] =
            fmaf(mj.x, v1.x, fmaf(mj.y, v1.y, fmaf(mj.z, v1.z, mj.w * v1.w)));

        if (j == 0) out[i] = S1[g][i];
    }
}

__global__ __launch_bounds__(256) void mlp1_kernel(
    const float* __restrict__ sig, const float* __restrict__ w1,
    float* __restrict__ hpart)
{
    __shared__ float s_sig[64 * 70];

    const int bx  = blockIdx.x;
    const int kc  = bx >> 2;
    const int hh  = bx & 3;
    const int tid = threadIdx.x;
    const int hq  = tid & 15;
    const int bg  = tid >> 4;

    const int k0   = kc * KLEN;
    const int klen = min(KLEN, SIG_TOT - k0);

    for (int idx = tid; idx < 64 * KLEN; idx += 256) {
        const int rb = idx / KLEN, kk = idx - rb * KLEN;
        if (kk < klen)
            s_sig[rb * 70 + kk] = sig[(size_t)rb * SIG_TOT + k0 + kk];
    }
    __syncthreads();

    float4 acc0 = make_float4(0.f, 0.f, 0.f, 0.f);
    float4 acc1 = acc0, acc2 = acc0, acc3 = acc0;

    const float* wp = w1 + (size_t)k0 * HIDDEN + hh * 64 + hq * 4;
    #pragma unroll 4
    for (int k = 0; k < klen; ++k) {
        const float4 wv = *(const float4*)(wp + (size_t)k * HIDDEN);
        const float sv0 = s_sig[(bg     ) * 70 + k];
        const float sv1 = s_sig[(bg + 16) * 70 + k];
        const float sv2 = s_sig[(bg + 32) * 70 + k];
        const float sv3 = s_sig[(bg + 48) * 70 + k];
        acc0.x = fmaf(sv0, wv.x, acc0.x); acc0.y = fmaf(sv0, wv.y, acc0.y);
        acc0.z = fmaf(sv0, wv.z, acc0.z); acc0.w = fmaf(sv0, wv.w, acc0.w);
        acc1.x = fmaf(sv1, wv.x, acc1.x); acc1.y = fmaf(sv1, wv.y, acc1.y);
        acc1.z = fmaf(sv1, wv.z, acc1.z); acc1.w = fmaf(sv1, wv.w, acc1.w);
        acc2.x = fmaf(sv2, wv.x, acc2.x); acc2.y = fmaf(sv2, wv.y, acc2.y);
        acc2.z = fmaf(sv2, wv.z, acc2.z); acc2.w = fmaf(sv2, wv.w, acc2.w);
        acc3.x = fmaf(sv3, wv.x, acc3.x); acc3.y = fmaf(sv3, wv.y, acc3.y);
        acc3.z = fmaf(sv3, wv.z, acc3.z); acc3.w = fmaf(sv3, wv.w, acc3.w);
    }

    const int hcol = hh * 64 + hq * 4;
    *(float4*)(hpart + ((size_t)kc * 64 + bg     ) * HIDDEN + hcol) = acc0;
    *(float4*)(hpart + ((size_t)kc * 64 + bg + 16) * HIDDEN + hcol) = acc1;
    *(float4*)(hpart + ((size_t)kc * 64 + bg + 32) * HIDDEN + hcol) = acc2;
    *(float4*)(hpart + ((size_t)kc * 64 + bg + 48) * HIDDEN + hcol) = acc3;
}

__global__ __launch_bounds__(1024) void mlp2_kernel(
    const float* __restrict__ hpart, const float* __restrict__ b1,
    const float* __restrict__ w2, const float* __restrict__ b2,
    float* __restrict__ outp)
{
    const int b   = blockIdx.x;
    const int tid = threadIdx.x;
    const int h   = tid & 255, q = tid >> 8;

    __shared__ float sp[4][HIDDEN];
    __shared__ float s_h[HIDDEN];
    __shared__ float s_p[8][33];

    float acc = 0.f;
    #pragma unroll 8
    for (int m = 0; m < 32; ++m) {
        const int kc = q * 32 + m;
        acc += hpart[((size_t)kc * 64 + b) * HIDDEN + h];
    }
    sp[q][h] = acc;
    __syncthreads();

    if (tid < HIDDEN) {
        const float v = b1[tid] + sp[0][tid] + sp[1][tid] + sp[2][tid] + sp[3][tid];
        s_h[tid] = fmaxf(v, 0.f);
    }
    __syncthreads();

    if (tid < 256) {
        const int o = tid & 31, part = tid >> 5;
        float p = 0.f;
        #pragma unroll
        for (int jj = 0; jj < 32; ++jj)
            p = fmaf(s_h[part * 32 + jj], w2[(part * 32 + jj) * OUT_CH + o], p);
        s_p[part][o] = p;
    }
    __syncthreads();

    if (tid < OUT_CH) {
        float oacc = b2[tid];
        #pragma unroll
        for (int pp = 0; pp < 8; ++pp) oacc += s_p[pp][tid];
        outp[b * OUT_CH + tid] = oacc;
    }
}

extern "C" void kernel_launch(void* const* d_in, const int* in_sizes, int n_in,
                              void* d_out, int out_size, void* d_ws, size_t ws_size,
                              hipStream_t stream) {
    const float* x       = (const float*)d_in[0];
    const void*  lengths = d_in[1];
    const float* aug_w   = (const float*)d_in[2];
    // d_in[3] = aug_b: bias cancels in increments, unused.
    const float* w1      = (const float*)d_in[4];
    const float* b1      = (const float*)d_in[5];
    const float* w2      = (const float*)d_in[6];
    const float* b2      = (const float*)d_in[7];

    float* sig   = (float*)d_ws;                                    // 2,236,416 B
    float* hpart = (float*)((char*)d_ws + (size_t)B_SZ * SIG_TOT * 4); // 8 MB
    float* outp  = (float*)d_out;

    void* kargs[] = { (void*)&x, (void*)&lengths, (void*)&aug_w, (void*)&w1,
                      (void*)&b1, (void*)&w2, (void*)&b2,
                      (void*)&sig, (void*)&hpart, (void*)&outp };
    hipError_t e = hipLaunchCooperativeKernel((void*)fused_all, dim3(256), dim3(1024),
                                              kargs, 0, stream);
    if (e != hipSuccess) {
        // deterministic fallback: verified 3-kernel path
        sig_fused_kernel<<<B_SZ, 1024, 0, stream>>>(x, lengths, aug_w, sig);
        mlp1_kernel<<<512, 256, 0, stream>>>(sig, w1, hpart);
        mlp2_kernel<<<B_SZ, 1024, 0, stream>>>(hpart, b1, w2, b2, outp);
    }
}

// Round 5
// 41.344 us; speedup vs baseline: 2.2246x; 2.2246x over previous
//
#include <hip/hip_runtime.h>

#define S_LEN   512
#define NSTEP   511
#define B_SZ    64
#define SIG_TOT 8736
#define HIDDEN  256
#define OUT_CH  32

// ws layout: C[64][88] at byte 0 (22528 B); wt[2][84][256] at byte 22528 (172032 B).
#define WT_OFF  22528

// ---------------------------------------------------------------------------
// Kernel 1: (a) depth-3 CORE signature of u = [1/511, dx] (4 channels) per
// batch element -> C[b][88]  ([0,4) c1, [4,20) c2 a*4+b, [20,84) c3 a*16+b*4+c).
// (b) transform w1 by M_g^{(x)k}: block bid owns cols [bid*4, bid*4+4):
//     wt1[a][col]   = sum_i M[i,a] w1[g*4368 + i][col]
//     wt2[ab][col]  = sum_ij M[i,a]M[j,b] w1[g*4368 + 16 + i*16+j][col]
//     wt3[abc][col] = sum_ijk M[i,a]M[j,b]M[k,c] w1[g*4368 + 272 + (i*16+j)*16+k][col]
// Then h = b1 + sum_g C . wt_g, exactly matching sig @ w1 (reordered fp32).
// ---------------------------------------------------------------------------
__global__ __launch_bounds__(1024) void sig_w1_kernel(
    const float* __restrict__ x,          // (64, 512, 3)
    const void*  __restrict__ lengths_raw,// (64,) int32 or int64
    const float* __restrict__ aug_w,      // (2, 12, 3)
    const float* __restrict__ w1,         // (8736, 256)
    float* __restrict__ c_ws,             // (64, 88)
    float* __restrict__ wt)               // (2, 84, 256)
{
    __shared__ alignas(16) float xs[S_LEN * 3];     // 6144 B
    __shared__ alignas(16) float u[NSTEP * 4 + 4];  // 8192 B
    __shared__ float segsig[16 * 88];               // 5632 B
    __shared__ float cs[88];
    __shared__ alignas(16) float M[2][16][4];       // [g][row][a]
    __shared__ alignas(16) float U[256 * 16];       // [ij][ck*4+col4] 16 KB
    __shared__ alignas(16) float V[16 * 64];        // [i][cj*16+ck*4+col4] 4 KB
    __shared__ alignas(16) float U2[16 * 16];       // [i][cb*4+col4] 1 KB

    const int bid = blockIdx.x;
    const int b   = bid;
    const int tid = threadIdx.x;

    // lengths dtype detect: all lengths >= 2 -> if word1 == 0 it's int64.
    const int* l32 = (const int*)lengths_raw;
    const int  len = (l32[1] == 0) ? l32[2 * b] : l32[b];
    const int  lastIdx = len - 1;

    // --- stage x, build M ---
    if (tid < 384)
        ((float4*)xs)[tid] = ((const float4*)(x + (size_t)b * S_LEN * 3))[tid];
    if (tid >= 512 && tid < 544) {
        const int t2 = tid - 512, g = t2 >> 4, row = t2 & 15;
        float4 m;
        if (row == 0)      m = make_float4(1.f, 0.f, 0.f, 0.f);
        else if (row < 4)  m = make_float4(0.f, row == 1 ? 1.f : 0.f,
                                                row == 2 ? 1.f : 0.f,
                                                row == 3 ? 1.f : 0.f);
        else {
            const float* aw = aug_w + g * 36 + (row - 4) * 3;
            m = make_float4(0.f, aw[0], aw[1], aw[2]);
        }
        *(float4*)&M[g][row][0] = m;
    }
    __syncthreads();

    // --- build u (masked increments; time channel never masked) ---
    if (tid < NSTEP) {
        const int s = tid;
        float dx0 = 0.f, dx1 = 0.f, dx2 = 0.f;
        if (s < lastIdx) {                 // become-constant trick => dx = 0
            dx0 = xs[(s + 1) * 3 + 0] - xs[s * 3 + 0];
            dx1 = xs[(s + 1) * 3 + 1] - xs[s * 3 + 1];
            dx2 = xs[(s + 1) * 3 + 2] - xs[s * 3 + 2];
        }
        *(float4*)&u[s * 4] = make_float4(1.0f / 511.0f, dx0, dx1, dx2);
    }
    __syncthreads();

    // --- per-wave 32-step core segment scan (thread = tensor index (a,bb,c)) ---
    const int wid  = tid >> 6, lane = tid & 63;
    const int a    = lane >> 4;
    const int bb   = (lane >> 2) & 3;
    const int c    = lane & 3;
    {
        const int s0   = wid * 32;
        const int nloc = min(32, NSTEP - s0);   // 32 (waves 0-14), 31 (wave 15)
        float r1 = 0.f, r2 = 0.f, r3 = 0.f;
        for (int s = s0; s < s0 + nloc; ++s) {
            const float da = u[s * 4 + a];
            const float db = u[s * 4 + bb];
            const float dc = u[s * 4 + c];
            const float t  = fmaf(db, fmaf(r1, 0.5f, da * (1.f / 6.f)), r2);
            r3 = fmaf(t, dc, r3);
            r2 = fmaf(db, fmaf(da, 0.5f, r1), r2);
            r1 += da;
        }
        segsig[wid * 88 + 20 + lane] = r3;
        if (c == 0)            segsig[wid * 88 + 4 + a * 4 + bb] = r2;
        if (bb == 0 && c == 0) segsig[wid * 88 + a]              = r1;
    }
    __syncthreads();

    // --- wave 0: serial Chen combine of 16 segments ---
    if (wid == 0) {
        float A1 = segsig[a];
        float A2 = segsig[4 + a * 4 + bb];
        float A3 = segsig[20 + lane];
        for (int sg = 1; sg < 16; ++sg) {
            const float* S = &segsig[sg * 88];
            const float B1a  = S[a];
            const float B1b  = S[bb];
            const float B1c  = S[c];
            const float B2ab = S[4 + a * 4 + bb];
            const float B2bc = S[4 + bb * 4 + c];
            const float B3   = S[20 + lane];
            A3 = fmaf(A1, B2bc, fmaf(A2, B1c, A3 + B3));  // OLD A1, A2
            A2 = fmaf(A1, B1b, A2 + B2ab);                // OLD A1
            A1 = A1 + B1a;
        }
        cs[20 + lane] = A3;
        if (c == 0)            cs[4 + a * 4 + bb] = A2;
        if (bb == 0 && c == 0) cs[a]              = A1;
    }
    __syncthreads();

    // --- write core signature to global ---
    if (tid < 84) c_ws[b * 88 + tid] = cs[tid];

    // --- W~ transform: block owns 4 columns, loop over groups ---
    const int col4 = tid & 3;
    const int gcol = bid * 4 + col4;

    for (int g = 0; g < 2; ++g) {
        const int gbase = g * 4368;
        __syncthreads();   // protect U/V/U2 reuse across g

        // stage A: contract k.  thread: (ij = tid>>2, col4)
        {
            const int ij = tid >> 2;
            const float* wp = w1 + (size_t)(gbase + 272 + ij * 16) * HIDDEN + gcol;
            float wk[16];
            #pragma unroll
            for (int k = 0; k < 16; ++k) wk[k] = wp[(size_t)k * HIDDEN];
            #pragma unroll
            for (int ck = 0; ck < 4; ++ck) {
                float acc = 0.f;
                #pragma unroll
                for (int k = 0; k < 16; ++k) acc = fmaf(M[g][k][ck], wk[k], acc);
                U[ij * 16 + ck * 4 + col4] = acc;
            }
        }
        __syncthreads();

        // stage B: contract j -> V; threads <256 also do level-2 stage 1 -> U2
        {
            const int rem = tid >> 2;
            const int i = rem >> 4, cj = (rem >> 2) & 3, ck = rem & 3;
            float acc = 0.f;
            #pragma unroll
            for (int j = 0; j < 16; ++j)
                acc = fmaf(M[g][j][cj], U[(i * 16 + j) * 16 + ck * 4 + col4], acc);
            V[i * 64 + cj * 16 + ck * 4 + col4] = acc;
        }
        if (tid < 256) {
            const int q = tid >> 2;
            const int i = q >> 2, cb = q & 3;
            const float* wp = w1 + (size_t)(gbase + 16 + i * 16) * HIDDEN + gcol;
            float acc = 0.f;
            #pragma unroll
            for (int j = 0; j < 16; ++j)
                acc = fmaf(M[g][j][cb], wp[(size_t)j * HIDDEN], acc);
            U2[i * 16 + cb * 4 + col4] = acc;
        }
        __syncthreads();

        // stage C: contract i -> wt3; plus wt2, wt1
        if (tid < 256) {
            const int rem = tid >> 2;                    // 0..63 = ci*16+cj*4+ck
            const int ci = rem >> 4, cj = (rem >> 2) & 3, ck = rem & 3;
            float acc = 0.f;
            #pragma unroll
            for (int i = 0; i < 16; ++i)
                acc = fmaf(M[g][i][ci], V[i * 64 + cj * 16 + ck * 4 + col4], acc);
            wt[(size_t)(g * 84 + 20 + rem) * HIDDEN + gcol] = acc;
        } else if (tid < 320) {
            const int tt = tid - 256;
            const int cl = tt & 3, ab = tt >> 2;         // ab = a*4 + bq
            const int aa = ab >> 2, bq = ab & 3;
            float acc = 0.f;
            #pragma unroll
            for (int i = 0; i < 16; ++i)
                acc = fmaf(M[g][i][aa], U2[i * 16 + bq * 4 + cl], acc);
            wt[(size_t)(g * 84 + 4 + ab) * HIDDEN + bid * 4 + cl] = acc;
        } else if (tid < 336) {
            const int tt = tid - 320;
            const int cl = tt & 3, aa = tt >> 2;
            const float* wp = w1 + (size_t)gbase * HIDDEN + bid * 4 + cl;
            float acc = 0.f;
            #pragma unroll
            for (int i = 0; i < 16; ++i)
                acc = fmaf(M[g][i][aa], wp[(size_t)i * HIDDEN], acc);
            wt[(size_t)(g * 84 + aa) * HIDDEN + bid * 4 + cl] = acc;
        }
    }
}

// ---------------------------------------------------------------------------
// Kernel 2: per batch b: h = b1 + sum_g C[b] . wt_g  (168 FMA/thread,
// coalesced wt reads), ReLU, then h @ w2 + b2 (verified 8-way split).
// ---------------------------------------------------------------------------
__global__ __launch_bounds__(256) void mlp_kernel(
    const float* __restrict__ c_ws,  // (64, 88)
    const float* __restrict__ wt,    // (2, 84, 256)
    const float* __restrict__ b1,    // (256,)
    const float* __restrict__ w2,    // (256, 32)
    const float* __restrict__ b2,    // (32,)
    float* __restrict__ outp)        // (64, 32)
{
    __shared__ float s_C[88];
    __shared__ float s_h[HIDDEN];
    __shared__ float s_p[8][33];

    const int b   = blockIdx.x;
    const int tid = threadIdx.x;

    if (tid < 84) s_C[tid] = c_ws[b * 88 + tid];
    __syncthreads();

    float acc = b1[tid];
    #pragma unroll
    for (int g = 0; g < 2; ++g) {
        #pragma unroll 6
        for (int idx = 0; idx < 84; ++idx)
            acc = fmaf(s_C[idx], wt[(size_t)(g * 84 + idx) * HIDDEN + tid], acc);
    }
    s_h[tid] = fmaxf(acc, 0.f);
    __syncthreads();

    const int o = tid & 31, part = tid >> 5;
    float p = 0.f;
    #pragma unroll
    for (int jj = 0; jj < 32; ++jj)
        p = fmaf(s_h[part * 32 + jj], w2[(part * 32 + jj) * OUT_CH + o], p);
    s_p[part][o] = p;
    __syncthreads();

    if (tid < OUT_CH) {
        float oacc = b2[tid];
        #pragma unroll
        for (int pp = 0; pp < 8; ++pp) oacc += s_p[pp][tid];
        outp[b * OUT_CH + tid] = oacc;
    }
}

extern "C" void kernel_launch(void* const* d_in, const int* in_sizes, int n_in,
                              void* d_out, int out_size, void* d_ws, size_t ws_size,
                              hipStream_t stream) {
    const float* x       = (const float*)d_in[0];
    const void*  lengths = d_in[1];
    const float* aug_w   = (const float*)d_in[2];
    // d_in[3] = aug_b: bias cancels in increments, unused.
    const float* w1      = (const float*)d_in[4];
    const float* b1      = (const float*)d_in[5];
    const float* w2      = (const float*)d_in[6];
    const float* b2      = (const float*)d_in[7];

    float* c_ws = (float*)d_ws;                       // 64*88*4   = 22528 B
    float* wt   = (float*)((char*)d_ws + WT_OFF);     // 2*84*256*4 = 172032 B

    sig_w1_kernel<<<B_SZ, 1024, 0, stream>>>(x, lengths, aug_w, w1, c_ws, wt);
    mlp_kernel<<<B_SZ, 256, 0, stream>>>(c_ws, wt, b1, w2, b2, (float*)d_out);
}